// Round 16
// baseline (91.273 us; speedup 1.0000x reference)
//
#include <hip/hip_runtime.h>
#include <math.h>
#include <stdint.h>

#define RESO 128
#define NUM_FEAT 16
#define DATA_DIM 16
#define MLP_W 128
#define NFREQ 4
#define BATCH 1024
#define NS 442
#define NT 256
#define NWAVES 4
#define STEPF ((float)(1.3 / 128.0))
// DIAGNOSTIC BUILD: body runs 4x (opaque rep) so the main kernel (~107us)
// clears the ~78us harness poison-fills and lands top-1 in rocprof.
#define NREP 4

typedef __attribute__((ext_vector_type(8))) short short8;
typedef __attribute__((ext_vector_type(4))) float f32x4;
typedef __attribute__((ext_vector_type(4))) int int4v;

static __device__ __forceinline__ unsigned short f2bf(float f) {
    union { float f; uint32_t u; } v; v.f = f;
    uint32_t r = v.u + 0x7FFFu + ((v.u >> 16) & 1u);   // round-nearest-even
    return (unsigned short)(r >> 16);
}
static __device__ __forceinline__ uint32_t pack2bf(float a, float b) {
    return (uint32_t)f2bf(a) | ((uint32_t)f2bf(b) << 16);
}

// ---------------- Morton ----------------
static __device__ __forceinline__ uint32_t expand_bits(uint32_t v) {
    v = (v * 65537u) & 4278190335u;
    v = (v * 257u)   & 251719695u;
    v = (v * 17u)    & 3272356035u;
    v = (v * 5u)     & 1227133513u;
    return v;
}

// ---- Main: one block (256 thr, 4 waves) per ray; 2 sample slots/thread ----
__global__ __launch_bounds__(NT) void nerf_main_kernel(
    const float* __restrict__ rays_o, const float* __restrict__ rays_d,
    const float* __restrict__ grid, const float* __restrict__ cbg,
    const float* __restrict__ W1g, const float* __restrict__ b1g,
    const float* __restrict__ W2g, const float* __restrict__ b2g,
    float* __restrict__ out_rgb, float* __restrict__ out_alpha) {

    __shared__ __align__(16) float cbs[NUM_FEAT * DATA_DIM];
    __shared__ __align__(16) float pe_b1s[MLP_W];              // b1[h] + pe . W1[16:40, h]
    __shared__ __align__(16) float W2s[MLP_W * 4];
    __shared__ __align__(16) unsigned short W1pL[8 * 64 * 8];  // packed A-fragments, 8 KB
    __shared__ float wtot[2][NWAVES];
    __shared__ float wred[NWAVES][4];

    const int b = blockIdx.x;
    const int t = threadIdx.x;
    const int wid = t >> 6;
    const int lane = t & 63;
    const int g = lane >> 4;

    // per-ray setup (broadcast loads)
    const float o0 = rays_o[b * 3 + 0], o1 = rays_o[b * 3 + 1], o2 = rays_o[b * 3 + 2];
    const float d0 = rays_d[b * 3 + 0], d1 = rays_d[b * 3 + 1], d2 = rays_d[b * 3 + 2];
    const float R = 1.3f;
    float sd0 = (fabsf(d0) < 1e-8f) ? 1e-8f : d0;
    float sd1 = (fabsf(d1) < 1e-8f) ? 1e-8f : d1;
    float sd2 = (fabsf(d2) < 1e-8f) ? 1e-8f : d2;
    float ta0 = (-R - o0) / sd0, tb0 = (R - o0) / sd0;
    float ta1 = (-R - o1) / sd1, tb1 = (R - o1) / sd1;
    float ta2 = (-R - o2) / sd2, tb2 = (R - o2) / sd2;
    float tmin = fmaxf(fmaxf(fminf(ta0, tb0), fminf(ta1, tb1)), fminf(ta2, tb2));
    float tmax = fminf(fminf(fmaxf(ta0, tb0), fmaxf(ta1, tb1)), fmaxf(ta2, tb2));
    float tnear0 = fmaxf(tmin, 0.0f);
    float nrm = sqrtf(d0 * d0 + d1 * d1 + d2 * d2);

    cbs[t] = cbg[t];
    W2s[t] = W2g[t];
    W2s[NT + t] = W2g[NT + t];

    // pack A-fragments of W1d^T into LDS: A[h][k]=W1[k][h] (k<16 else 0)
    for (int idx = t; idx < 8 * 64 * 8; idx += NT) {
        int j = idx & 7, l = (idx >> 3) & 63, mh = idx >> 9;
        int k = (l >> 4) * 8 + j;
        float v = (k < DATA_DIM) ? W1g[k * MLP_W + mh * 16 + (l & 15)] : 0.0f;
        W1pL[idx] = f2bf(v);
    }

    // fold positional encoding + b1 into per-ray bias (exact f32)
    if (t < MLP_W) {
        float acc = b1g[t];
#pragma unroll
        for (int f = 0; f < NFREQ; ++f) {
            float fr = (float)(1 << f);
            acc = fmaf(__sinf(d0 * fr), W1g[(DATA_DIM + f * 6 + 0) * MLP_W + t], acc);
            acc = fmaf(__sinf(d1 * fr), W1g[(DATA_DIM + f * 6 + 1) * MLP_W + t], acc);
            acc = fmaf(__sinf(d2 * fr), W1g[(DATA_DIM + f * 6 + 2) * MLP_W + t], acc);
            acc = fmaf(__cosf(d0 * fr), W1g[(DATA_DIM + f * 6 + 3) * MLP_W + t], acc);
            acc = fmaf(__cosf(d1 * fr), W1g[(DATA_DIM + f * 6 + 4) * MLP_W + t], acc);
            acc = fmaf(__cosf(d2 * fr), W1g[(DATA_DIM + f * 6 + 5) * MLP_W + t], acc);
        }
        pe_b1s[t] = acc;
    }
    __syncthreads();

    for (int rep = 0; rep < NREP; ++rep) {
        float tnear = tnear0;
        asm volatile("" : "+v"(tnear));    // opaque: no CSE/hoist across reps

        // ---- per-slot heavy path (gather + MFMA MLP), wave-skippable ----
        auto process = [&](int s, float& alpha, float& c0, float& c1, float& c2) {
            float i0 = tnear + (float)s * STEPF;
            float tm = i0 + 0.5f * STEPF;
            float delta = STEPF * nrm;
            float px = o0 + d0 * tm, py = o1 + d1 * tm, pz = o2 + d2 * tm;
            bool m = (s < NS) && (tm < tmax) &&
                     (fabsf(px) <= R) && (fabsf(py) <= R) && (fabsf(pz) <= R);
            alpha = 0.0f; c0 = 0.0f; c1 = 0.0f; c2 = 0.0f;
            if (!__any((int)m)) return;

            float x[DATA_DIM];
#pragma unroll
            for (int j = 0; j < DATA_DIM; ++j) x[j] = 0.0f;

            if (m) {
                float gx = (px / R + 1.0f) * (RESO * 0.5f);
                float gy = (py / R + 1.0f) * (RESO * 0.5f);
                float gz = (pz / R + 1.0f) * (RESO * 0.5f);
                float flx = floorf(gx), fly = floorf(gy), flz = floorf(gz);
                float ox = gx - flx, oy = gy - fly, oz = gz - flz;
                int ix = (int)flx, iy = (int)fly, iz = (int)flz;

                int ix0 = min(max(ix, 0), RESO - 1), ix1 = min(max(ix + 1, 0), RESO - 1);
                int iy0 = min(max(iy, 0), RESO - 1), iy1 = min(max(iy + 1, 0), RESO - 1);
                int iz0 = min(max(iz, 0), RESO - 1), iz1 = min(max(iz + 1, 0), RESO - 1);
                uint32_t ex0 = expand_bits((uint32_t)ix0), ex1 = expand_bits((uint32_t)ix1);
                uint32_t ey0 = expand_bits((uint32_t)iy0) << 1, ey1 = expand_bits((uint32_t)iy1) << 1;
                uint32_t ez0 = expand_bits((uint32_t)iz0) << 2, ez1 = expand_bits((uint32_t)iz1) << 2;
                float wx0 = 1.0f - ox, wy0 = 1.0f - oy, wz0 = 1.0f - oz;

#pragma unroll
                for (int n = 0; n < 8; ++n) {
                    int bx = (n >> 2) & 1, by = (n >> 1) & 1, bz = n & 1;
                    uint32_t mi = (bx ? ex1 : ex0) | (by ? ey1 : ey0) | (bz ? ez1 : ez0);
                    float wv = (bx ? ox : wx0) * (by ? oy : wy0) * (bz ? oz : wz0);

                    const float4* g4 = (const float4*)(grid + ((size_t)mi << 4));
                    float4 A = g4[0], B = g4[1], C = g4[2], D = g4[3];
                    float v[16] = {A.x, A.y, A.z, A.w, B.x, B.y, B.z, B.w,
                                   C.x, C.y, C.z, C.w, D.x, D.y, D.z, D.w};
                    float bestv = v[0];
                    int bi = 0;
#pragma unroll
                    for (int j = 1; j < 16; ++j) {
                        bi = (v[j] > bestv) ? j : bi;
                        bestv = fmaxf(v[j], bestv);
                    }

                    const float4* cbr = (const float4*)&cbs[bi * DATA_DIM];
                    float4 ca = cbr[0], cb4 = cbr[1], cc = cbr[2], cd = cbr[3];
                    x[0]  = fmaf(wv, ca.x,  x[0]);  x[1]  = fmaf(wv, ca.y,  x[1]);
                    x[2]  = fmaf(wv, ca.z,  x[2]);  x[3]  = fmaf(wv, ca.w,  x[3]);
                    x[4]  = fmaf(wv, cb4.x, x[4]);  x[5]  = fmaf(wv, cb4.y, x[5]);
                    x[6]  = fmaf(wv, cb4.z, x[6]);  x[7]  = fmaf(wv, cb4.w, x[7]);
                    x[8]  = fmaf(wv, cc.x,  x[8]);  x[9]  = fmaf(wv, cc.y,  x[9]);
                    x[10] = fmaf(wv, cc.z,  x[10]); x[11] = fmaf(wv, cc.w,  x[11]);
                    x[12] = fmaf(wv, cd.x,  x[12]); x[13] = fmaf(wv, cd.y,  x[13]);
                    x[14] = fmaf(wv, cd.z,  x[14]); x[15] = fmaf(wv, cd.w,  x[15]);
                }
            }

            // MFMA MLP (per-wave, transposed)
            uint32_t wp[8];
#pragma unroll
            for (int i = 0; i < 8; ++i) wp[i] = pack2bf(x[2 * i], x[2 * i + 1]);

            short8 Bf[4];
#pragma unroll
            for (int ns = 0; ns < 4; ++ns) {
                int src = ns * 16 + (lane & 15);
                int v0a = __shfl((int)wp[0], src, 64), v0b = __shfl((int)wp[4], src, 64);
                int v1a = __shfl((int)wp[1], src, 64), v1b = __shfl((int)wp[5], src, 64);
                int v2a = __shfl((int)wp[2], src, 64), v2b = __shfl((int)wp[6], src, 64);
                int v3a = __shfl((int)wp[3], src, 64), v3b = __shfl((int)wp[7], src, 64);
                union { int4v i; short8 s; } u;
                u.i.x = (g == 0) ? v0a : (g == 1) ? v0b : 0;
                u.i.y = (g == 0) ? v1a : (g == 1) ? v1b : 0;
                u.i.z = (g == 0) ? v2a : (g == 1) ? v2b : 0;
                u.i.w = (g == 0) ? v3a : (g == 1) ? v3b : 0;
                Bf[ns] = u.s;
            }

            float p[4][4];
#pragma unroll
            for (int ns = 0; ns < 4; ++ns)
#pragma unroll
                for (int c = 0; c < 4; ++c) p[ns][c] = 0.0f;

            const int4v* Ap = (const int4v*)W1pL;
#pragma unroll
            for (int mh = 0; mh < 8; ++mh) {
                union { int4v i; short8 s; } ua;
                ua.i = Ap[mh * 64 + lane];
                short8 Af = ua.s;

                f32x4 bias = *(const f32x4*)&pe_b1s[mh * 16 + 4 * g];
                f32x4 accv[4];
                accv[0] = __builtin_amdgcn_mfma_f32_16x16x32_bf16(Af, Bf[0], bias, 0, 0, 0);
                accv[1] = __builtin_amdgcn_mfma_f32_16x16x32_bf16(Af, Bf[1], bias, 0, 0, 0);
                accv[2] = __builtin_amdgcn_mfma_f32_16x16x32_bf16(Af, Bf[2], bias, 0, 0, 0);
                accv[3] = __builtin_amdgcn_mfma_f32_16x16x32_bf16(Af, Bf[3], bias, 0, 0, 0);

                float4 w2r[4];
                w2r[0] = *(const float4*)&W2s[(mh * 16 + 4 * g + 0) * 4];   // LDS broadcast
                w2r[1] = *(const float4*)&W2s[(mh * 16 + 4 * g + 1) * 4];
                w2r[2] = *(const float4*)&W2s[(mh * 16 + 4 * g + 2) * 4];
                w2r[3] = *(const float4*)&W2s[(mh * 16 + 4 * g + 3) * 4];
#pragma unroll
                for (int ns = 0; ns < 4; ++ns) {
#pragma unroll
                    for (int r = 0; r < 4; ++r) {
                        float h = fmaxf(accv[ns][r], 0.0f);
                        float4 wr2 = w2r[r];
                        p[ns][0] = fmaf(h, wr2.x, p[ns][0]);
                        p[ns][1] = fmaf(h, wr2.y, p[ns][1]);
                        p[ns][2] = fmaf(h, wr2.z, p[ns][2]);
                        p[ns][3] = fmaf(h, wr2.w, p[ns][3]);
                    }
                }
            }

#pragma unroll
            for (int ns = 0; ns < 4; ++ns)
#pragma unroll
                for (int c = 0; c < 4; ++c) {
                    float v = p[ns][c];
                    v += __shfl_xor(v, 16, 64);
                    v += __shfl_xor(v, 32, 64);
                    p[ns][c] = v;
                }

            float pre[4];
#pragma unroll
            for (int c = 0; c < 4; ++c) {
                float v = (g == 0) ? p[0][c] : (g == 1) ? p[1][c] : (g == 2) ? p[2][c] : p[3][c];
                pre[c] = v + b2g[c];
            }

            if (m) {
                float dens = fmaxf(pre[0], 0.0f);
                alpha = 1.0f - __expf(-dens * delta);
                c0 = 1.0f / (1.0f + __expf(-pre[1]));
                c1 = 1.0f / (1.0f + __expf(-pre[2]));
                c2 = 1.0f / (1.0f + __expf(-pre[3]));
            }
        };

        float alphaA, c0A, c1A, c2A, alphaB, c0B, c1B, c2B;
        process(t, alphaA, c0A, c1A, c2A);            // samples 0..255
        process(NT + t, alphaB, c0B, c1B, c2B);       // samples 256..511 (mostly skipped)

        // ---- compositing: two chained chunks, wave scans + cross-wave combine ----
        float incA = 1.0f - alphaA + 1e-10f;
        float incB = 1.0f - alphaB + 1e-10f;
#pragma unroll
        for (int off = 1; off < 64; off <<= 1) {
            float uA = __shfl_up(incA, off, 64);
            float uB = __shfl_up(incB, off, 64);
            if (lane >= off) { incA *= uA; incB *= uB; }
        }
        float exclA = __shfl_up(incA, 1, 64);
        float exclB = __shfl_up(incB, 1, 64);
        if (lane == 0) { exclA = 1.0f; exclB = 1.0f; }
        if (lane == 63) { wtot[0][wid] = incA; wtot[1][wid] = incB; }
        __syncthreads();

        float wpreA = 1.0f;
#pragma unroll
        for (int w = 0; w < NWAVES; ++w)
            if (w < wid) wpreA *= wtot[0][w];
        float PA = wtot[0][0] * wtot[0][1] * wtot[0][2] * wtot[0][3];
        float wpreB = PA;
#pragma unroll
        for (int w = 0; w < NWAVES; ++w)
            if (w < wid) wpreB *= wtot[1][w];

        float wgtA = alphaA * wpreA * exclA;
        float wgtB = alphaB * wpreB * exclB;
        float r0 = wgtA * c0A + wgtB * c0B;
        float r1 = wgtA * c1A + wgtB * c1B;
        float r2 = wgtA * c2A + wgtB * c2B;
        float rw = wgtA + wgtB;

        out_alpha[b * NS + t] = alphaA;
        if (t < NS - NT) out_alpha[b * NS + NT + t] = alphaB;

        // ---- final rgb reduction ----
#pragma unroll
        for (int off = 32; off >= 1; off >>= 1) {
            r0 += __shfl_down(r0, off, 64);
            r1 += __shfl_down(r1, off, 64);
            r2 += __shfl_down(r2, off, 64);
            rw += __shfl_down(rw, off, 64);
        }
        if (lane == 0) { wred[wid][0] = r0; wred[wid][1] = r1; wred[wid][2] = r2; wred[wid][3] = rw; }
        __syncthreads();
        if (t == 0) {
            float s0 = 0, s1 = 0, s2 = 0, sw = 0;
#pragma unroll
            for (int i = 0; i < NWAVES; ++i) {
                s0 += wred[i][0]; s1 += wred[i][1]; s2 += wred[i][2]; sw += wred[i][3];
            }
            float bg = 1.0f - sw;
            out_rgb[b * 3 + 0] = s0 + bg;
            out_rgb[b * 3 + 1] = s1 + bg;
            out_rgb[b * 3 + 2] = s2 + bg;
        }
        __syncthreads();   // protect wtot/wred across reps
    }
}

extern "C" void kernel_launch(void* const* d_in, const int* in_sizes, int n_in,
                              void* d_out, int out_size, void* d_ws, size_t ws_size,
                              hipStream_t stream) {
    const float* rays_o   = (const float*)d_in[0];
    const float* rays_d   = (const float*)d_in[1];
    const float* grid     = (const float*)d_in[2];
    const float* codebook = (const float*)d_in[3];
    const float* W1       = (const float*)d_in[4];
    const float* b1       = (const float*)d_in[5];
    const float* W2       = (const float*)d_in[6];
    const float* b2       = (const float*)d_in[7];
    float* out = (float*)d_out;

    nerf_main_kernel<<<BATCH, NT, 0, stream>>>(
        rays_o, rays_d, grid, codebook, W1, b1, W2, b2,
        out /* rgb: 1024*3 */, out + BATCH * 3 /* alpha: 1024*442 */);
}

// Round 17
// 39.773 us; speedup vs baseline: 2.2949x; 2.2949x over previous
//
#include <hip/hip_runtime.h>
#include <math.h>
#include <stdint.h>

#define RESO 128
#define NUM_FEAT 16
#define DATA_DIM 16
#define MLP_W 128
#define NFREQ 4
#define BATCH 1024
#define NS 442
#define CPR 7                      // chunks per ray (7*64 = 448 >= 442)
#define NENT (BATCH * CPR)         // 7168 wave work-items
#define STEPF ((float)(1.3 / 128.0))

typedef __attribute__((ext_vector_type(8))) short short8;
typedef __attribute__((ext_vector_type(4))) float f32x4;
typedef __attribute__((ext_vector_type(4))) int int4v;

static __device__ __forceinline__ unsigned short f2bf(float f) {
    union { float f; uint32_t u; } v; v.f = f;
    uint32_t r = v.u + 0x7FFFu + ((v.u >> 16) & 1u);   // round-nearest-even
    return (unsigned short)(r >> 16);
}
static __device__ __forceinline__ uint32_t pack2bf(float a, float b) {
    return (uint32_t)f2bf(a) | ((uint32_t)f2bf(b) << 16);
}

// ---------------- Morton ----------------
static __device__ __forceinline__ uint32_t expand_bits(uint32_t v) {
    v = (v * 65537u) & 4278190335u;
    v = (v * 257u)   & 251719695u;
    v = (v * 17u)    & 3272356035u;
    v = (v * 5u)     & 1227133513u;
    return v;
}

// ---- Prep: per-ray pe.W1+b1 bias (1024x128) + packed W1 A-fragments ----
__global__ __launch_bounds__(128) void prep_kernel(
    const float* __restrict__ rays_d, const float* __restrict__ W1,
    const float* __restrict__ b1, float* __restrict__ peB,
    unsigned short* __restrict__ W1p) {
    const int b = blockIdx.x;
    const int t = threadIdx.x;
    const float d0 = rays_d[b * 3 + 0], d1 = rays_d[b * 3 + 1], d2 = rays_d[b * 3 + 2];
    float acc = b1[t];
#pragma unroll
    for (int f = 0; f < NFREQ; ++f) {
        float fr = (float)(1 << f);
        acc = fmaf(__sinf(d0 * fr), W1[(DATA_DIM + f * 6 + 0) * MLP_W + t], acc);
        acc = fmaf(__sinf(d1 * fr), W1[(DATA_DIM + f * 6 + 1) * MLP_W + t], acc);
        acc = fmaf(__sinf(d2 * fr), W1[(DATA_DIM + f * 6 + 2) * MLP_W + t], acc);
        acc = fmaf(__cosf(d0 * fr), W1[(DATA_DIM + f * 6 + 3) * MLP_W + t], acc);
        acc = fmaf(__cosf(d1 * fr), W1[(DATA_DIM + f * 6 + 4) * MLP_W + t], acc);
        acc = fmaf(__cosf(d2 * fr), W1[(DATA_DIM + f * 6 + 5) * MLP_W + t], acc);
    }
    peB[b * MLP_W + t] = acc;
    if (b == 0) {
        // pack A-fragments of W1d^T: A[h][k]=W1[k][h] (k<16 else 0);
        // tile mh, lane l: row h = 16*mh+(l&15), k = (l>>4)*8 + j
        for (int idx = t; idx < 8 * 64 * 8; idx += 128) {
            int j = idx & 7, l = (idx >> 3) & 63, mh = idx >> 9;
            int k = (l >> 4) * 8 + j;
            float v = (k < DATA_DIM) ? W1[k * MLP_W + mh * 16 + (l & 15)] : 0.0f;
            W1p[idx] = f2bf(v);
        }
    }
}

// ---- Main: one 64-thread block = one (ray, chunk) wave item; no LDS/barriers ----
__global__ __launch_bounds__(64) void nerf_main_kernel(
    const float* __restrict__ rays_o, const float* __restrict__ rays_d,
    const float* __restrict__ grid, const float* __restrict__ cbg,
    const float* __restrict__ W2g, const float* __restrict__ b2g,
    const float* __restrict__ peB, const unsigned short* __restrict__ W1p,
    float* __restrict__ part, float* __restrict__ out_alpha) {

    const int e = blockIdx.x;          // work item, < NENT
    const int b = e / CPR;
    const int c = e - b * CPR;
    const int lane = threadIdx.x;
    const int g = lane >> 4;

    // per-ray setup (wave-uniform addresses; L1 broadcast)
    const float o0 = rays_o[b * 3 + 0], o1 = rays_o[b * 3 + 1], o2 = rays_o[b * 3 + 2];
    const float d0 = rays_d[b * 3 + 0], d1 = rays_d[b * 3 + 1], d2 = rays_d[b * 3 + 2];
    const float R = 1.3f;
    float sd0 = (fabsf(d0) < 1e-8f) ? 1e-8f : d0;
    float sd1 = (fabsf(d1) < 1e-8f) ? 1e-8f : d1;
    float sd2 = (fabsf(d2) < 1e-8f) ? 1e-8f : d2;
    float ta0 = (-R - o0) / sd0, tb0 = (R - o0) / sd0;
    float ta1 = (-R - o1) / sd1, tb1 = (R - o1) / sd1;
    float ta2 = (-R - o2) / sd2, tb2 = (R - o2) / sd2;
    float tmin = fmaxf(fmaxf(fminf(ta0, tb0), fminf(ta1, tb1)), fminf(ta2, tb2));
    float tmax = fminf(fminf(fmaxf(ta0, tb0), fmaxf(ta1, tb1)), fmaxf(ta2, tb2));
    float tnear = fmaxf(tmin, 0.0f);
    float nrm = sqrtf(d0 * d0 + d1 * d1 + d2 * d2);

    const int s = c * 64 + lane;
    float tm = tnear + ((float)s + 0.5f) * STEPF;
    float delta = STEPF * nrm;
    float px = o0 + d0 * tm, py = o1 + d1 * tm, pz = o2 + d2 * tm;
    bool m = (s < NS) && (tm < tmax) &&
             (fabsf(px) <= R) && (fabsf(py) <= R) && (fabsf(pz) <= R);

    if (!__any((int)m)) {
        // inactive chunk: zero alphas + identity partial, fast exit
        if (s < NS) out_alpha[b * NS + s] = 0.0f;
        if (lane == 0) {
            float* P = part + (size_t)e * 8;
            P[0] = 0.0f; P[1] = 0.0f; P[2] = 0.0f; P[3] = 0.0f; P[4] = 1.0f;
        }
        return;
    }

    float alpha = 0.0f, c0 = 0.0f, c1 = 0.0f, c2 = 0.0f;

    float x[DATA_DIM];
#pragma unroll
    for (int j = 0; j < DATA_DIM; ++j) x[j] = 0.0f;

    if (m) {
        float gx = (px / R + 1.0f) * (RESO * 0.5f);
        float gy = (py / R + 1.0f) * (RESO * 0.5f);
        float gz = (pz / R + 1.0f) * (RESO * 0.5f);
        float flx = floorf(gx), fly = floorf(gy), flz = floorf(gz);
        float ox = gx - flx, oy = gy - fly, oz = gz - flz;
        int ix = (int)flx, iy = (int)fly, iz = (int)flz;

        // explicit CSE: 6 expand_bits per sample, pre-shifted
        int ix0 = min(max(ix, 0), RESO - 1), ix1 = min(max(ix + 1, 0), RESO - 1);
        int iy0 = min(max(iy, 0), RESO - 1), iy1 = min(max(iy + 1, 0), RESO - 1);
        int iz0 = min(max(iz, 0), RESO - 1), iz1 = min(max(iz + 1, 0), RESO - 1);
        uint32_t ex0 = expand_bits((uint32_t)ix0), ex1 = expand_bits((uint32_t)ix1);
        uint32_t ey0 = expand_bits((uint32_t)iy0) << 1, ey1 = expand_bits((uint32_t)iy1) << 1;
        uint32_t ez0 = expand_bits((uint32_t)iz0) << 2, ez1 = expand_bits((uint32_t)iz1) << 2;
        float wx0 = 1.0f - ox, wy0 = 1.0f - oy, wz0 = 1.0f - oz;

#pragma unroll
        for (int n = 0; n < 8; ++n) {
            int bx = (n >> 2) & 1, by = (n >> 1) & 1, bz = n & 1;
            uint32_t mi = (bx ? ex1 : ex0) | (by ? ey1 : ey0) | (bz ? ez1 : ez0);
            float wv = (bx ? ox : wx0) * (by ? oy : wy0) * (bz ? oz : wz0);

            const float4* g4 = (const float4*)(grid + ((size_t)mi << 4));
            float4 A = g4[0], B = g4[1], C = g4[2], D = g4[3];
            float v[16] = {A.x, A.y, A.z, A.w, B.x, B.y, B.z, B.w,
                           C.x, C.y, C.z, C.w, D.x, D.y, D.z, D.w};
            float bestv = v[0];
            int bi = 0;
#pragma unroll
            for (int j = 1; j < 16; ++j) {
                bi = (v[j] > bestv) ? j : bi;
                bestv = fmaxf(v[j], bestv);
            }

            const float4* cbr = (const float4*)(cbg + bi * DATA_DIM);   // 1KB, L1-hot
            float4 ca = cbr[0], cb4 = cbr[1], cc = cbr[2], cd = cbr[3];
            x[0]  = fmaf(wv, ca.x,  x[0]);  x[1]  = fmaf(wv, ca.y,  x[1]);
            x[2]  = fmaf(wv, ca.z,  x[2]);  x[3]  = fmaf(wv, ca.w,  x[3]);
            x[4]  = fmaf(wv, cb4.x, x[4]);  x[5]  = fmaf(wv, cb4.y, x[5]);
            x[6]  = fmaf(wv, cb4.z, x[6]);  x[7]  = fmaf(wv, cb4.w, x[7]);
            x[8]  = fmaf(wv, cc.x,  x[8]);  x[9]  = fmaf(wv, cc.y,  x[9]);
            x[10] = fmaf(wv, cc.z,  x[10]); x[11] = fmaf(wv, cc.w,  x[11]);
            x[12] = fmaf(wv, cd.x,  x[12]); x[13] = fmaf(wv, cd.y,  x[13]);
            x[14] = fmaf(wv, cd.z,  x[14]); x[15] = fmaf(wv, cd.w,  x[15]);
        }
    }

    // ================= MFMA MLP (per-wave, transposed) =================
    {
        uint32_t wp[8];
#pragma unroll
        for (int i = 0; i < 8; ++i) wp[i] = pack2bf(x[2 * i], x[2 * i + 1]);

        short8 Bf[4];
#pragma unroll
        for (int ns = 0; ns < 4; ++ns) {
            int src = ns * 16 + (lane & 15);
            int v0a = __shfl((int)wp[0], src, 64), v0b = __shfl((int)wp[4], src, 64);
            int v1a = __shfl((int)wp[1], src, 64), v1b = __shfl((int)wp[5], src, 64);
            int v2a = __shfl((int)wp[2], src, 64), v2b = __shfl((int)wp[6], src, 64);
            int v3a = __shfl((int)wp[3], src, 64), v3b = __shfl((int)wp[7], src, 64);
            union { int4v i; short8 s; } u;
            u.i.x = (g == 0) ? v0a : (g == 1) ? v0b : 0;
            u.i.y = (g == 0) ? v1a : (g == 1) ? v1b : 0;
            u.i.z = (g == 0) ? v2a : (g == 1) ? v2b : 0;
            u.i.w = (g == 0) ? v3a : (g == 1) ? v3b : 0;
            Bf[ns] = u.s;
        }

        float p[4][4];
#pragma unroll
        for (int ns = 0; ns < 4; ++ns)
#pragma unroll
            for (int cc2 = 0; cc2 < 4; ++cc2) p[ns][cc2] = 0.0f;

        const int4v* Ap = (const int4v*)W1p;
        const float* peb = peB + b * MLP_W;
#pragma unroll
        for (int mh = 0; mh < 8; ++mh) {
            union { int4v i; short8 s; } ua;
            ua.i = Ap[mh * 64 + lane];          // 1KB/tile, L1/L2-hot
            short8 Af = ua.s;

            f32x4 bias = *(const f32x4*)(peb + mh * 16 + 4 * g);   // 4 addrs/wave, L1
            f32x4 accv[4];
            accv[0] = __builtin_amdgcn_mfma_f32_16x16x32_bf16(Af, Bf[0], bias, 0, 0, 0);
            accv[1] = __builtin_amdgcn_mfma_f32_16x16x32_bf16(Af, Bf[1], bias, 0, 0, 0);
            accv[2] = __builtin_amdgcn_mfma_f32_16x16x32_bf16(Af, Bf[2], bias, 0, 0, 0);
            accv[3] = __builtin_amdgcn_mfma_f32_16x16x32_bf16(Af, Bf[3], bias, 0, 0, 0);

            float4 w2r[4];
            w2r[0] = *(const float4*)(W2g + (mh * 16 + 4 * g + 0) * 4);   // 2KB, L1-hot
            w2r[1] = *(const float4*)(W2g + (mh * 16 + 4 * g + 1) * 4);
            w2r[2] = *(const float4*)(W2g + (mh * 16 + 4 * g + 2) * 4);
            w2r[3] = *(const float4*)(W2g + (mh * 16 + 4 * g + 3) * 4);
#pragma unroll
            for (int ns = 0; ns < 4; ++ns) {
#pragma unroll
                for (int r = 0; r < 4; ++r) {
                    float h = fmaxf(accv[ns][r], 0.0f);
                    float4 wr2 = w2r[r];
                    p[ns][0] = fmaf(h, wr2.x, p[ns][0]);
                    p[ns][1] = fmaf(h, wr2.y, p[ns][1]);
                    p[ns][2] = fmaf(h, wr2.z, p[ns][2]);
                    p[ns][3] = fmaf(h, wr2.w, p[ns][3]);
                }
            }
        }

        // butterfly over lane bits 4,5 (groups hold disjoint h-row sets)
#pragma unroll
        for (int ns = 0; ns < 4; ++ns)
#pragma unroll
            for (int cc2 = 0; cc2 < 4; ++cc2) {
                float v = p[ns][cc2];
                v += __shfl_xor(v, 16, 64);
                v += __shfl_xor(v, 32, 64);
                p[ns][cc2] = v;
            }

        float pre[4];
#pragma unroll
        for (int cc2 = 0; cc2 < 4; ++cc2) {
            float v = (g == 0) ? p[0][cc2] : (g == 1) ? p[1][cc2] : (g == 2) ? p[2][cc2] : p[3][cc2];
            pre[cc2] = v + b2g[cc2];
        }

        if (m) {
            float dens = fmaxf(pre[0], 0.0f);
            alpha = 1.0f - __expf(-dens * delta);
            c0 = 1.0f / (1.0f + __expf(-pre[1]));
            c1 = 1.0f / (1.0f + __expf(-pre[2]));
            c2 = 1.0f / (1.0f + __expf(-pre[3]));
        }
    }

    // ---- wave-local compositing: product scan (T relative to chunk start) ----
    float inc = 1.0f - alpha + 1e-10f;
#pragma unroll
    for (int off = 1; off < 64; off <<= 1) {
        float u = __shfl_up(inc, off, 64);
        if (lane >= off) inc *= u;
    }
    float excl = __shfl_up(inc, 1, 64);
    if (lane == 0) excl = 1.0f;
    float P = __shfl(inc, 63, 64);         // chunk transmittance product

    float wgt = alpha * excl;
    float r0 = wgt * c0, r1 = wgt * c1, r2 = wgt * c2, rw = wgt;

    if (s < NS) out_alpha[b * NS + s] = alpha;

#pragma unroll
    for (int off = 32; off >= 1; off >>= 1) {
        r0 += __shfl_down(r0, off, 64);
        r1 += __shfl_down(r1, off, 64);
        r2 += __shfl_down(r2, off, 64);
        rw += __shfl_down(rw, off, 64);
    }
    if (lane == 0) {
        float* Pp = part + (size_t)e * 8;
        Pp[0] = r0; Pp[1] = r1; Pp[2] = r2; Pp[3] = rw; Pp[4] = P;
    }
}

// -------- Combine: chain <=7 chunk partials per ray + white background --------
__global__ __launch_bounds__(256) void combine_kernel(const float* __restrict__ part,
                                                      float* __restrict__ out_rgb) {
    int b = blockIdx.x * 256 + threadIdx.x;
    if (b >= BATCH) return;
    float T = 1.0f, r0 = 0.0f, r1 = 0.0f, r2 = 0.0f, rw = 0.0f;
#pragma unroll
    for (int c = 0; c < CPR; ++c) {
        const float* P = part + (size_t)(b * CPR + c) * 8;
        r0 = fmaf(T, P[0], r0);
        r1 = fmaf(T, P[1], r1);
        r2 = fmaf(T, P[2], r2);
        rw = fmaf(T, P[3], rw);
        T *= P[4];
    }
    float bg = 1.0f - rw;
    out_rgb[b * 3 + 0] = r0 + bg;
    out_rgb[b * 3 + 1] = r1 + bg;
    out_rgb[b * 3 + 2] = r2 + bg;
}

extern "C" void kernel_launch(void* const* d_in, const int* in_sizes, int n_in,
                              void* d_out, int out_size, void* d_ws, size_t ws_size,
                              hipStream_t stream) {
    const float* rays_o   = (const float*)d_in[0];
    const float* rays_d   = (const float*)d_in[1];
    const float* grid     = (const float*)d_in[2];
    const float* codebook = (const float*)d_in[3];
    const float* W1       = (const float*)d_in[4];
    const float* b1       = (const float*)d_in[5];
    const float* W2       = (const float*)d_in[6];
    const float* b2       = (const float*)d_in[7];
    float* out = (float*)d_out;

    float* part = (float*)d_ws;                                   // 229 KB
    float* peB = (float*)((char*)d_ws + (size_t)NENT * 8 * 4);    // 512 KB
    unsigned short* W1p = (unsigned short*)((char*)peB + (size_t)BATCH * MLP_W * 4);  // 8 KB

    prep_kernel<<<BATCH, 128, 0, stream>>>(rays_d, W1, b1, peB, W1p);
    nerf_main_kernel<<<NENT, 64, 0, stream>>>(
        rays_o, rays_d, grid, codebook, W2, b2, peB, W1p,
        part, out + BATCH * 3 /* alpha: 1024*442 */);
    combine_kernel<<<(BATCH + 255) / 256, 256, 0, stream>>>(part, out /* rgb */);
}

// Round 18
// 26.624 us; speedup vs baseline: 3.4282x; 1.4938x over previous
//
#include <hip/hip_runtime.h>
#include <math.h>
#include <stdint.h>

#define RESO 128
#define NUM_FEAT 16
#define DATA_DIM 16
#define MLP_W 128
#define NFREQ 4
#define BATCH 1024
#define NS 442
#define NT 256
#define NWAVES 4
#define STEPF ((float)(1.3 / 128.0))

typedef __attribute__((ext_vector_type(8))) short short8;
typedef __attribute__((ext_vector_type(4))) float f32x4;
typedef __attribute__((ext_vector_type(4))) int int4v;

static __device__ __forceinline__ unsigned short f2bf(float f) {
    union { float f; uint32_t u; } v; v.f = f;
    uint32_t r = v.u + 0x7FFFu + ((v.u >> 16) & 1u);   // round-nearest-even
    return (unsigned short)(r >> 16);
}
static __device__ __forceinline__ uint32_t pack2bf(float a, float b) {
    return (uint32_t)f2bf(a) | ((uint32_t)f2bf(b) << 16);
}

// ---------------- Morton ----------------
static __device__ __forceinline__ uint32_t expand_bits(uint32_t v) {
    v = (v * 65537u) & 4278190335u;
    v = (v * 257u)   & 251719695u;
    v = (v * 17u)    & 3272356035u;
    v = (v * 5u)     & 1227133513u;
    return v;
}

// ---- Main: one block (256 thr, 4 waves) per ray; 2 sample slots/thread ----
__global__ __launch_bounds__(NT) void nerf_main_kernel(
    const float* __restrict__ rays_o, const float* __restrict__ rays_d,
    const float* __restrict__ grid, const float* __restrict__ cbg,
    const float* __restrict__ W1g, const float* __restrict__ b1g,
    const float* __restrict__ W2g, const float* __restrict__ b2g,
    float* __restrict__ out_rgb, float* __restrict__ out_alpha) {

    __shared__ __align__(16) float cbs[NUM_FEAT * DATA_DIM];
    __shared__ __align__(16) float pe_b1s[MLP_W];              // b1[h] + pe . W1[16:40, h]
    __shared__ __align__(16) float W2s[MLP_W * 4];
    __shared__ __align__(16) unsigned short W1pL[8 * 64 * 8];  // packed A-fragments, 8 KB
    __shared__ float wtot[2][NWAVES];
    __shared__ float wred[NWAVES][4];

    const int b = blockIdx.x;
    const int t = threadIdx.x;
    const int wid = t >> 6;
    const int lane = t & 63;
    const int g = lane >> 4;

    // per-ray setup (broadcast loads)
    const float o0 = rays_o[b * 3 + 0], o1 = rays_o[b * 3 + 1], o2 = rays_o[b * 3 + 2];
    const float d0 = rays_d[b * 3 + 0], d1 = rays_d[b * 3 + 1], d2 = rays_d[b * 3 + 2];
    const float R = 1.3f;
    float sd0 = (fabsf(d0) < 1e-8f) ? 1e-8f : d0;
    float sd1 = (fabsf(d1) < 1e-8f) ? 1e-8f : d1;
    float sd2 = (fabsf(d2) < 1e-8f) ? 1e-8f : d2;
    float ta0 = (-R - o0) / sd0, tb0 = (R - o0) / sd0;
    float ta1 = (-R - o1) / sd1, tb1 = (R - o1) / sd1;
    float ta2 = (-R - o2) / sd2, tb2 = (R - o2) / sd2;
    float tmin = fmaxf(fmaxf(fminf(ta0, tb0), fminf(ta1, tb1)), fminf(ta2, tb2));
    float tmax = fminf(fminf(fmaxf(ta0, tb0), fmaxf(ta1, tb1)), fmaxf(ta2, tb2));
    float tnear = fmaxf(tmin, 0.0f);
    float nrm = sqrtf(d0 * d0 + d1 * d1 + d2 * d2);

    cbs[t] = cbg[t];
    W2s[t] = W2g[t];
    W2s[NT + t] = W2g[NT + t];

    // pack A-fragments of W1d^T into LDS: A[h][k]=W1[k][h] (k<16 else 0)
    for (int idx = t; idx < 8 * 64 * 8; idx += NT) {
        int j = idx & 7, l = (idx >> 3) & 63, mh = idx >> 9;
        int k = (l >> 4) * 8 + j;
        float v = (k < DATA_DIM) ? W1g[k * MLP_W + mh * 16 + (l & 15)] : 0.0f;
        W1pL[idx] = f2bf(v);
    }

    // fold positional encoding + b1 into per-ray bias (exact f32)
    if (t < MLP_W) {
        float acc = b1g[t];
#pragma unroll
        for (int f = 0; f < NFREQ; ++f) {
            float fr = (float)(1 << f);
            acc = fmaf(__sinf(d0 * fr), W1g[(DATA_DIM + f * 6 + 0) * MLP_W + t], acc);
            acc = fmaf(__sinf(d1 * fr), W1g[(DATA_DIM + f * 6 + 1) * MLP_W + t], acc);
            acc = fmaf(__sinf(d2 * fr), W1g[(DATA_DIM + f * 6 + 2) * MLP_W + t], acc);
            acc = fmaf(__cosf(d0 * fr), W1g[(DATA_DIM + f * 6 + 3) * MLP_W + t], acc);
            acc = fmaf(__cosf(d1 * fr), W1g[(DATA_DIM + f * 6 + 4) * MLP_W + t], acc);
            acc = fmaf(__cosf(d2 * fr), W1g[(DATA_DIM + f * 6 + 5) * MLP_W + t], acc);
        }
        pe_b1s[t] = acc;
    }
    __syncthreads();

    // ---- per-slot heavy path (gather + MFMA MLP), wave-skippable ----
    auto process = [&](int s, float& alpha, float& c0, float& c1, float& c2) {
        float i0 = tnear + (float)s * STEPF;
        float tm = i0 + 0.5f * STEPF;
        float delta = STEPF * nrm;
        float px = o0 + d0 * tm, py = o1 + d1 * tm, pz = o2 + d2 * tm;
        bool m = (s < NS) && (tm < tmax) &&
                 (fabsf(px) <= R) && (fabsf(py) <= R) && (fabsf(pz) <= R);
        alpha = 0.0f; c0 = 0.0f; c1 = 0.0f; c2 = 0.0f;
        if (!__any((int)m)) return;

        float x[DATA_DIM];
#pragma unroll
        for (int j = 0; j < DATA_DIM; ++j) x[j] = 0.0f;

        if (m) {
            float gx = (px / R + 1.0f) * (RESO * 0.5f);
            float gy = (py / R + 1.0f) * (RESO * 0.5f);
            float gz = (pz / R + 1.0f) * (RESO * 0.5f);
            float flx = floorf(gx), fly = floorf(gy), flz = floorf(gz);
            float ox = gx - flx, oy = gy - fly, oz = gz - flz;
            int ix = (int)flx, iy = (int)fly, iz = (int)flz;

            // explicit CSE: 6 expand_bits per sample (2 per axis), pre-shifted
            int ix0 = min(max(ix, 0), RESO - 1), ix1 = min(max(ix + 1, 0), RESO - 1);
            int iy0 = min(max(iy, 0), RESO - 1), iy1 = min(max(iy + 1, 0), RESO - 1);
            int iz0 = min(max(iz, 0), RESO - 1), iz1 = min(max(iz + 1, 0), RESO - 1);
            uint32_t ex0 = expand_bits((uint32_t)ix0), ex1 = expand_bits((uint32_t)ix1);
            uint32_t ey0 = expand_bits((uint32_t)iy0) << 1, ey1 = expand_bits((uint32_t)iy1) << 1;
            uint32_t ez0 = expand_bits((uint32_t)iz0) << 2, ez1 = expand_bits((uint32_t)iz1) << 2;
            float wx0 = 1.0f - ox, wy0 = 1.0f - oy, wz0 = 1.0f - oz;

#pragma unroll
            for (int n = 0; n < 8; ++n) {
                int bx = (n >> 2) & 1, by = (n >> 1) & 1, bz = n & 1;
                uint32_t mi = (bx ? ex1 : ex0) | (by ? ey1 : ey0) | (bz ? ez1 : ez0);
                float wv = (bx ? ox : wx0) * (by ? oy : wy0) * (bz ? oz : wz0);

                const float4* g4 = (const float4*)(grid + ((size_t)mi << 4));
                float4 A = g4[0], B = g4[1], C = g4[2], D = g4[3];
                float v[16] = {A.x, A.y, A.z, A.w, B.x, B.y, B.z, B.w,
                               C.x, C.y, C.z, C.w, D.x, D.y, D.z, D.w};
                float bestv = v[0];
                int bi = 0;
#pragma unroll
                for (int j = 1; j < 16; ++j) {
                    bi = (v[j] > bestv) ? j : bi;
                    bestv = fmaxf(v[j], bestv);
                }

                const float4* cbr = (const float4*)&cbs[bi * DATA_DIM];
                float4 ca = cbr[0], cb4 = cbr[1], cc = cbr[2], cd = cbr[3];
                x[0]  = fmaf(wv, ca.x,  x[0]);  x[1]  = fmaf(wv, ca.y,  x[1]);
                x[2]  = fmaf(wv, ca.z,  x[2]);  x[3]  = fmaf(wv, ca.w,  x[3]);
                x[4]  = fmaf(wv, cb4.x, x[4]);  x[5]  = fmaf(wv, cb4.y, x[5]);
                x[6]  = fmaf(wv, cb4.z, x[6]);  x[7]  = fmaf(wv, cb4.w, x[7]);
                x[8]  = fmaf(wv, cc.x,  x[8]);  x[9]  = fmaf(wv, cc.y,  x[9]);
                x[10] = fmaf(wv, cc.z,  x[10]); x[11] = fmaf(wv, cc.w,  x[11]);
                x[12] = fmaf(wv, cd.x,  x[12]); x[13] = fmaf(wv, cd.y,  x[13]);
                x[14] = fmaf(wv, cd.z,  x[14]); x[15] = fmaf(wv, cd.w,  x[15]);
            }
        }

        // MFMA MLP (per-wave, transposed)
        uint32_t wp[8];
#pragma unroll
        for (int i = 0; i < 8; ++i) wp[i] = pack2bf(x[2 * i], x[2 * i + 1]);

        short8 Bf[4];
#pragma unroll
        for (int ns = 0; ns < 4; ++ns) {
            int src = ns * 16 + (lane & 15);
            int v0a = __shfl((int)wp[0], src, 64), v0b = __shfl((int)wp[4], src, 64);
            int v1a = __shfl((int)wp[1], src, 64), v1b = __shfl((int)wp[5], src, 64);
            int v2a = __shfl((int)wp[2], src, 64), v2b = __shfl((int)wp[6], src, 64);
            int v3a = __shfl((int)wp[3], src, 64), v3b = __shfl((int)wp[7], src, 64);
            union { int4v i; short8 s; } u;
            u.i.x = (g == 0) ? v0a : (g == 1) ? v0b : 0;
            u.i.y = (g == 0) ? v1a : (g == 1) ? v1b : 0;
            u.i.z = (g == 0) ? v2a : (g == 1) ? v2b : 0;
            u.i.w = (g == 0) ? v3a : (g == 1) ? v3b : 0;
            Bf[ns] = u.s;
        }

        float p[4][4];
#pragma unroll
        for (int ns = 0; ns < 4; ++ns)
#pragma unroll
            for (int c = 0; c < 4; ++c) p[ns][c] = 0.0f;

        const int4v* Ap = (const int4v*)W1pL;
#pragma unroll
        for (int mh = 0; mh < 8; ++mh) {
            union { int4v i; short8 s; } ua;
            ua.i = Ap[mh * 64 + lane];
            short8 Af = ua.s;

            f32x4 bias = *(const f32x4*)&pe_b1s[mh * 16 + 4 * g];
            f32x4 accv[4];
            accv[0] = __builtin_amdgcn_mfma_f32_16x16x32_bf16(Af, Bf[0], bias, 0, 0, 0);
            accv[1] = __builtin_amdgcn_mfma_f32_16x16x32_bf16(Af, Bf[1], bias, 0, 0, 0);
            accv[2] = __builtin_amdgcn_mfma_f32_16x16x32_bf16(Af, Bf[2], bias, 0, 0, 0);
            accv[3] = __builtin_amdgcn_mfma_f32_16x16x32_bf16(Af, Bf[3], bias, 0, 0, 0);

            float4 w2r[4];
            w2r[0] = *(const float4*)&W2s[(mh * 16 + 4 * g + 0) * 4];   // LDS broadcast
            w2r[1] = *(const float4*)&W2s[(mh * 16 + 4 * g + 1) * 4];
            w2r[2] = *(const float4*)&W2s[(mh * 16 + 4 * g + 2) * 4];
            w2r[3] = *(const float4*)&W2s[(mh * 16 + 4 * g + 3) * 4];
#pragma unroll
            for (int ns = 0; ns < 4; ++ns) {
#pragma unroll
                for (int r = 0; r < 4; ++r) {
                    float h = fmaxf(accv[ns][r], 0.0f);
                    float4 wr2 = w2r[r];
                    p[ns][0] = fmaf(h, wr2.x, p[ns][0]);
                    p[ns][1] = fmaf(h, wr2.y, p[ns][1]);
                    p[ns][2] = fmaf(h, wr2.z, p[ns][2]);
                    p[ns][3] = fmaf(h, wr2.w, p[ns][3]);
                }
            }
        }

#pragma unroll
        for (int ns = 0; ns < 4; ++ns)
#pragma unroll
            for (int c = 0; c < 4; ++c) {
                float v = p[ns][c];
                v += __shfl_xor(v, 16, 64);
                v += __shfl_xor(v, 32, 64);
                p[ns][c] = v;
            }

        float pre[4];
#pragma unroll
        for (int c = 0; c < 4; ++c) {
            float v = (g == 0) ? p[0][c] : (g == 1) ? p[1][c] : (g == 2) ? p[2][c] : p[3][c];
            pre[c] = v + b2g[c];
        }

        if (m) {
            float dens = fmaxf(pre[0], 0.0f);
            alpha = 1.0f - __expf(-dens * delta);
            c0 = 1.0f / (1.0f + __expf(-pre[1]));
            c1 = 1.0f / (1.0f + __expf(-pre[2]));
            c2 = 1.0f / (1.0f + __expf(-pre[3]));
        }
    };

    float alphaA, c0A, c1A, c2A, alphaB, c0B, c1B, c2B;
    process(t, alphaA, c0A, c1A, c2A);            // samples 0..255
    process(NT + t, alphaB, c0B, c1B, c2B);       // samples 256..511 (mostly skipped)

    // ---- compositing: two chained chunks, wave scans + cross-wave combine ----
    float incA = 1.0f - alphaA + 1e-10f;
    float incB = 1.0f - alphaB + 1e-10f;
#pragma unroll
    for (int off = 1; off < 64; off <<= 1) {
        float uA = __shfl_up(incA, off, 64);
        float uB = __shfl_up(incB, off, 64);
        if (lane >= off) { incA *= uA; incB *= uB; }
    }
    float exclA = __shfl_up(incA, 1, 64);
    float exclB = __shfl_up(incB, 1, 64);
    if (lane == 0) { exclA = 1.0f; exclB = 1.0f; }
    if (lane == 63) { wtot[0][wid] = incA; wtot[1][wid] = incB; }
    __syncthreads();

    float wpreA = 1.0f;
#pragma unroll
    for (int w = 0; w < NWAVES; ++w)
        if (w < wid) wpreA *= wtot[0][w];
    float PA = wtot[0][0] * wtot[0][1] * wtot[0][2] * wtot[0][3];
    float wpreB = PA;
#pragma unroll
    for (int w = 0; w < NWAVES; ++w)
        if (w < wid) wpreB *= wtot[1][w];

    float wgtA = alphaA * wpreA * exclA;
    float wgtB = alphaB * wpreB * exclB;
    float r0 = wgtA * c0A + wgtB * c0B;
    float r1 = wgtA * c1A + wgtB * c1B;
    float r2 = wgtA * c2A + wgtB * c2B;
    float rw = wgtA + wgtB;

    out_alpha[b * NS + t] = alphaA;
    if (t < NS - NT) out_alpha[b * NS + NT + t] = alphaB;

    // ---- final rgb reduction ----
#pragma unroll
    for (int off = 32; off >= 1; off >>= 1) {
        r0 += __shfl_down(r0, off, 64);
        r1 += __shfl_down(r1, off, 64);
        r2 += __shfl_down(r2, off, 64);
        rw += __shfl_down(rw, off, 64);
    }
    if (lane == 0) { wred[wid][0] = r0; wred[wid][1] = r1; wred[wid][2] = r2; wred[wid][3] = rw; }
    __syncthreads();
    if (t == 0) {
        float s0 = 0, s1 = 0, s2 = 0, sw = 0;
#pragma unroll
        for (int i = 0; i < NWAVES; ++i) {
            s0 += wred[i][0]; s1 += wred[i][1]; s2 += wred[i][2]; sw += wred[i][3];
        }
        float bg = 1.0f - sw;
        out_rgb[b * 3 + 0] = s0 + bg;
        out_rgb[b * 3 + 1] = s1 + bg;
        out_rgb[b * 3 + 2] = s2 + bg;
    }
}

extern "C" void kernel_launch(void* const* d_in, const int* in_sizes, int n_in,
                              void* d_out, int out_size, void* d_ws, size_t ws_size,
                              hipStream_t stream) {
    const float* rays_o   = (const float*)d_in[0];
    const float* rays_d   = (const float*)d_in[1];
    const float* grid     = (const float*)d_in[2];
    const float* codebook = (const float*)d_in[3];
    const float* W1       = (const float*)d_in[4];
    const float* b1       = (const float*)d_in[5];
    const float* W2       = (const float*)d_in[6];
    const float* b2       = (const float*)d_in[7];
    float* out = (float*)d_out;

    nerf_main_kernel<<<BATCH, NT, 0, stream>>>(
        rays_o, rays_d, grid, codebook, W1, b1, W2, b2,
        out /* rgb: 1024*3 */, out + BATCH * 3 /* alpha: 1024*442 */);
}